// Round 2
// baseline (110.401 us; speedup 1.0000x reference)
//
#include <hip/hip_runtime.h>

#define EPSF 1e-9f

constexpr int I   = 144;    // 9*16 input capsules
constexpr int IC  = 36;     // i's per chunk (4 chunks per wave)
constexpr int RT  = 148;    // s_zr row stride (144 + 4 pad)
constexpr int SP  = 20;     // s_pose row stride (16 + 4 pad)
constexpr int QS  = 68;     // s_q row stride (64 + 4 pad, 16B-aligned)

// Intra-quad reductions on the VALU pipe (DPP quad_perm), NOT the DS pipe.
// 0xB1 = quad_perm [1,0,3,2] (xor 1), 0x4E = quad_perm [2,3,0,1] (xor 2).
// 0x124 = row_ror:4, 0x128 = row_ror:8 (rows are 16 lanes on gfx9/CDNA).
__device__ __forceinline__ float dpp_xor1(float x) {
    return __int_as_float(__builtin_amdgcn_update_dpp(0, __float_as_int(x), 0xB1, 0xF, 0xF, true));
}
__device__ __forceinline__ float dpp_xor2(float x) {
    return __int_as_float(__builtin_amdgcn_update_dpp(0, __float_as_int(x), 0x4E, 0xF, 0xF, true));
}
__device__ __forceinline__ float quad_sum(float x) {
    float y = x + dpp_xor1(x);
    return y + dpp_xor2(y);
}
__device__ __forceinline__ float quad_max(float x) {
    float y = fmaxf(x, dpp_xor1(x));
    return fmaxf(y, dpp_xor2(y));
}
// Full sum across the 16-lane row (= all p for fixed chunk), entirely on VALU:
// quad ladder leaves [AAAA BBBB CCCC DDDD]; +ror4 then +ror8 -> total in all lanes.
__device__ __forceinline__ float row_sum16(float x) {
    float y = quad_sum(x);
    int a = __builtin_amdgcn_update_dpp(0, __float_as_int(y), 0x124, 0xF, 0xF, true);
    y += __int_as_float(a);
    a = __builtin_amdgcn_update_dpp(0, __float_as_int(y), 0x128, 0xF, 0xF, true);
    return y + __int_as_float(a);
}
// x + value-from-lane^16 / lane^32, on the VALU pipe (gfx950 permlane*_swap).
// With both operands = x, the result pair {r0,r1} holds {own, partner} in some
// order in every lane, so r0+r1 is direction-agnostic. Falls back to shfl (DS).
__device__ __forceinline__ float add_xor16(float x) {
#if __has_builtin(__builtin_amdgcn_permlane16_swap)
    auto r = __builtin_amdgcn_permlane16_swap(__float_as_int(x), __float_as_int(x), false, false);
    return __int_as_float(r[0]) + __int_as_float(r[1]);
#else
    return x + __shfl_xor(x, 16);
#endif
}
__device__ __forceinline__ float add_xor32(float x) {
#if __has_builtin(__builtin_amdgcn_permlane32_swap)
    auto r = __builtin_amdgcn_permlane32_swap(__float_as_int(x), __float_as_int(x), false, false);
    return __int_as_float(r[0]) + __int_as_float(r[1]);
#else
    return x + __shfl_xor(x, 32);
#endif
}
// Fast 1/x (v_rcp_f32, ~1 ulp): fine under the 2e-2 absmax threshold.
__device__ __forceinline__ float frcp(float x) { return __builtin_amdgcn_rcpf(x); }
// Raw hardware log2/exp2 (v_log_f32 / v_exp_f32). All EM logs/exps run in
// base-2 domain; ln2 is folded into `a`, inv_temp and cost_sum once.
__device__ __forceinline__ float flog2(float x) {
#if __has_builtin(__builtin_amdgcn_logf)
    return __builtin_amdgcn_logf(x);
#else
    return __log2f(x);
#endif
}
__device__ __forceinline__ float fexp2(float x) {
#if __has_builtin(__builtin_amdgcn_exp2f)
    return __builtin_amdgcn_exp2f(x);
#else
    return exp2f(x);
#endif
}

#define LN2F     0.69314718056f
#define INV_LN2F 1.44269504089f

// wt[i,o,pc,q] = w[i,o,q,pc]  -> vote loop reads one float4 per (i, lane)
__global__ void transpose_w_kernel(const float* __restrict__ w, float* __restrict__ wt) {
    const int i = blockIdx.x;
    const int t = threadIdx.x;                  // t = o*16 + q*4 + pc
    const float val = w[i * 256 + t];
    const int o = t >> 4, q = (t >> 2) & 3, pc = t & 3;
    wt[i * 256 + o * 16 + pc * 4 + q] = val;
}

// Block = 1024 = 16 waves; wave = one o. lane = c*16 + p (c = i-chunk, p = pose elem).
// M-step reductions fully in-wave (permlane16/32_swap pairs for chunks, DPP
// row_sum16 for p). E-step: keep/send DPP butterfly gives lane pc the quad-sum
// of slot pc in 12 insts (vs 4x quad_sum + 3 cndmask = 19); 9 unmasked
// ds_write_b32 per thread.
// NOTE (R7/R10): fp32 pk-packing is neutral-to-negative here (build-vector movs
// or no dur gain despite lower busy). Keep scalar + DPP.
// NOTE (R8): '#pragma unroll' on the 3-iter EM loop REGRESSED (3x hot-body
// code size -> I-fetch stalls). Keep the loop ROLLED (unroll 1).
// NOTE (R11): slog/cq p-sums use row_ror DPP (VALU) instead of shfl_xor 4/8
// (DS) — the epilogue is a full-wave serial chain; DS shuffle latency there
// is pure stall.
// launch_bounds (1024,4): 128-VGPR cap. (1024,8) capped at 32 VGPR in R3 and
// spilled the vote array -> 394 MB scratch traffic. Do not tighten.
template <bool USE_WT>
__global__ __launch_bounds__(1024, 4)
void capsule_em_kernel(const float* __restrict__ pose_in,   // [8,14,14,256]
                       const float* __restrict__ act_in,    // [8,14,14,16]
                       const float* __restrict__ wmat,      // wt (transposed) or w
                       const float* __restrict__ beta_v,    // [16]
                       const float* __restrict__ beta_a,    // [16]
                       float* __restrict__ out)             // pose 294912 | act 18432
{
    __shared__ __align__(16) float s_pose[I * SP];   // 11520 B
    __shared__ __align__(16) float s_zr[16 * RT];    //  9472 B  rr' [o][i]
    __shared__ __align__(16) float s_q[I * QS];      // 39168 B  q partials [i][o*4+pr]
    __shared__ __align__(16) float s_iact[I + 4];    //   592 B
    __shared__ float s_Lo[16];                       //    64 B

    const int tid  = threadIdx.x;
    const int o    = tid >> 6;          // wave id
    const int lane = tid & 63;
    const int c    = lane >> 4;
    const int p    = lane & 15;
    const int pr   = p >> 2;
    const int pc   = p & 3;
    const int i0   = c * IC;
    const bool pb0 = pc & 1;
    const bool pb1 = pc & 2;

    const int n   = blockIdx.x;
    const int b   = n / 144;
    const int rem = n - b * 144;
    const int hp  = rem / 12;
    const int wp  = rem - hp * 12;

    // ---- stage pose patch (9 x 256 floats, float4) + i_act ----
    if (tid < 576) {
        const int pk = tid >> 6, l6 = tid & 63;
        const int ki = pk / 3, kj = pk - ki * 3;
        const float4 val = *reinterpret_cast<const float4*>(
            &pose_in[((b * 14 + hp + ki) * 14 + (wp + kj)) * 256 + l6 * 4]);
        const int i = pk * 16 + (l6 >> 2), e = (l6 & 3) * 4;
        *reinterpret_cast<float4*>(&s_pose[i * SP + e]) = val;
    } else if (tid < 720) {
        const int t = tid - 576;
        const int pk = t >> 4, ic = t & 15;
        const int ki = pk / 3, kj = pk - ki * 3;
        s_iact[t] = act_in[((b * 14 + hp + ki) * 14 + (wp + kj)) * 16 + ic];
    }
    __syncthreads();

    // ---- votes: v[ii] = sum_q pose[i,pr,q] * w[i,o,q,pc], i = i0+ii ----
    float v[IC];
    #pragma unroll
    for (int ii = 0; ii < IC; ++ii) {
        const int i = i0 + ii;
        const float4 pv = *reinterpret_cast<const float4*>(&s_pose[i * SP + pr * 4]);
        if (USE_WT) {
            const float4 wv = *reinterpret_cast<const float4*>(&wmat[i * 256 + o * 16 + pc * 4]);
            v[ii] = pv.x * wv.x + pv.y * wv.y + pv.z * wv.z + pv.w * wv.w;
        } else {
            const float* wb = &wmat[i * 256 + o * 16 + pc];
            v[ii] = pv.x * wb[0] + pv.y * wb[4] + pv.z * wb[8] + pv.w * wb[12];
        }
    }

    const float bv = beta_v[o];
    const float ba = beta_a[o];

    float mean = 0.0f, o_act = 0.0f;

    #pragma unroll 1
    for (int it = 0; it < 3; ++it) {
        // ---------------- M-step (wave-autonomous, no barriers) ----------------
        float accS = 0.0f, acc1 = 0.0f, acc2 = 0.0f;
        const float* rrow = (it == 0) ? &s_iact[i0] : &s_zr[o * RT + i0];
        #pragma unroll
        for (int jj = 0; jj < 9; ++jj) {
            const float4 r4 = *reinterpret_cast<const float4*>(&rrow[jj * 4]);
            const float r[4] = {r4.x, r4.y, r4.z, r4.w};
            #pragma unroll
            for (int k = 0; k < 4; ++k) {
                const float t = r[k] * v[jj * 4 + k];
                accS += r[k];
                acc1 += t;
                acc2 += t * v[jj * 4 + k];
            }
        }
        // cross-chunk sums on the VALU pipe (permlane swaps), not DS shuffles
        accS = add_xor16(accS); accS = add_xor32(accS);
        acc1 = add_xor16(acc1); acc1 = add_xor32(acc1);
        acc2 = add_xor16(acc2); acc2 = add_xor32(acc2);
        if (it == 0) {   // iter-0 rr' = iact/16: fold 1/16 after reduction
            accS *= 0.0625f; acc1 *= 0.0625f; acc2 *= 0.0625f;
        }

        const float inv = frcp(accS + EPSF);
        mean = acc1 * inv;
        float var = (acc2 - 2.0f * mean * acc1 + mean * mean * accS) * inv;
        var = fmaxf(var, 0.0f);
        // log(sigma+1e-9) == 0.5*log(var+1e-18) (exact in both limits) -> no sqrt.
        // slog2 is kept in LOG2 domain; ln2 applied once in cost_sum.
        const float slog2 = row_sum16(0.5f * flog2(var + 1e-18f));  // all on VALU

        const float cost_sum = accS * (16.0f * bv + LN2F * slog2);
        const float it2 = INV_LN2F * (1.0f + (float)it);   // inv_temp folded w/ 1/ln2
        o_act = frcp(1.0f + fexp2(-it2 * (ba - cost_sum)));

        // ---------------- E-step (skip on last iter) ----------------
        if (it < 2) {
            // Whole E-step runs in log2 domain: a2 = (1/ln2)/(2*var+eps), so the
            // quadratic terms, cq and Lo are all log2-scaled; softmax is
            // base-invariant and uses raw v_exp_f32.
            const float a2  = INV_LN2F * frcp(2.0f * var + EPSF);
            const float b22 = 2.0f * mean * a2;
            const float cq2 = row_sum16(mean * mean * a2);
            const float Lo  = flog2(o_act + EPSF) - slog2 - cq2;
            if (lane == 0) s_Lo[o] = Lo;
            #pragma unroll
            for (int j = 0; j < 9; ++j) {
                float ct[4];
                #pragma unroll
                for (int t = 0; t < 4; ++t) {
                    const float vv = v[4 * j + t];
                    ct[t] = vv * fmaf(vv, a2, -b22);     // (v^2 - 2*mean*v) * a2
                }
                // keep/send transpose-butterfly: lane pc ends with the quad-sum
                // (over pose-cols) of slot pc. 6 cndmask + 3 DPP + 3 add.
                const float k01 = pb0 ? ct[1] : ct[0];
                const float s01 = pb0 ? ct[0] : ct[1];
                const float k23 = pb0 ? ct[3] : ct[2];
                const float s23 = pb0 ? ct[2] : ct[3];
                const float a01 = k01 + dpp_xor1(s01);
                const float a23 = k23 + dpp_xor1(s23);
                const float kk  = pb1 ? a23 : a01;
                const float ss  = pb1 ? a01 : a23;
                const float val = kk + dpp_xor2(ss);
                // lane (c,pr,pc) writes vote i0+4j+pc's pr-partial: unmasked b32
                s_q[(i0 + 4 * j + pc) * QS + o * 4 + pr] = val;
            }
            __syncthreads();
            // softmax over o per i: 576 threads, 4 o's each (quad ladders on VALU)
            if (tid < 576) {
                const int si = tid >> 2, sj = tid & 3;
                float zz[4];
                #pragma unroll
                for (int k = 0; k < 4; ++k) {
                    const float4 qv = *reinterpret_cast<const float4*>(
                        &s_q[si * QS + (sj * 4 + k) * 4]);
                    zz[k] = s_Lo[sj * 4 + k] - (qv.x + qv.y + qv.z + qv.w);
                }
                float m = fmaxf(fmaxf(zz[0], zz[1]), fmaxf(zz[2], zz[3]));
                m = quad_max(m);
                const float e0 = fexp2(zz[0] - m), e1 = fexp2(zz[1] - m);
                const float e2 = fexp2(zz[2] - m), e3 = fexp2(zz[3] - m);
                const float s = quad_sum(e0 + e1 + e2 + e3);
                const float sc = s_iact[si] * frcp(s);    // fold i_act into rr'
                s_zr[(sj * 4 + 0) * RT + si] = e0 * sc;
                s_zr[(sj * 4 + 1) * RT + si] = e1 * sc;
                s_zr[(sj * 4 + 2) * RT + si] = e2 * sc;
                s_zr[(sj * 4 + 3) * RT + si] = e3 * sc;
            }
            __syncthreads();
        }
    }

    // ---- outputs ----
    if (c == 0) out[n * 256 + o * 16 + p] = mean;                // pose
    if (lane == 0) out[8 * 12 * 12 * 256 + n * 16 + o] = o_act;  // activation
}

extern "C" void kernel_launch(void* const* d_in, const int* in_sizes, int n_in,
                              void* d_out, int out_size, void* d_ws, size_t ws_size,
                              hipStream_t stream) {
    const float* pose = (const float*)d_in[0];
    const float* act  = (const float*)d_in[1];
    const float* w    = (const float*)d_in[2];
    const float* bv   = (const float*)d_in[3];
    const float* ba   = (const float*)d_in[4];
    float* out = (float*)d_out;

    const size_t wt_bytes = size_t(I) * 256 * sizeof(float);   // 147456
    if (ws_size >= wt_bytes) {
        float* wt = (float*)d_ws;
        transpose_w_kernel<<<dim3(I), dim3(256), 0, stream>>>(w, wt);
        capsule_em_kernel<true><<<dim3(1152), dim3(1024), 0, stream>>>(pose, act, wt, bv, ba, out);
    } else {
        capsule_em_kernel<false><<<dim3(1152), dim3(1024), 0, stream>>>(pose, act, w, bv, ba, out);
    }
}